// Round 1
// baseline (225.264 us; speedup 1.0000x reference)
//
#include <hip/hip_runtime.h>

#define ROWS_PER_BLOCK 128
#define THREADS 128
#define ROW_F 85        // floats per row
#define NCLS 80         // classes
#define CONF_THRESH 0.25f

// Block = 128 threads, 2 waves. Stages 128 contiguous rows (43,520 B, an exact
// multiple of 16 B) into LDS via coalesced float4 loads, then 1 thread/row
// scans its row out of LDS. LDS stride 85 floats -> t*85 % 32 = t*21 % 32 is a
// permutation over banks (21 odd) -> conflict-free.
__global__ __launch_bounds__(THREADS) void yolo_post_kernel(
    const float* __restrict__ in, float* __restrict__ out, int nrows) {
  __shared__ float tile[ROWS_PER_BLOCK * ROW_F];  // 10880 floats = 43,520 B

  const long long row0 = (long long)blockIdx.x * ROWS_PER_BLOCK;
  const long long base_f = row0 * ROW_F;                 // flat float offset
  const long long total_f = (long long)nrows * ROW_F;

  // ---- Stage: contiguous chunk -> LDS, float4 (2720 vec4 per block) ----
  const int tile_v = (ROWS_PER_BLOCK * ROW_F) / 4;       // 2720
  const float4* __restrict__ src = (const float4*)(in + base_f);
  float4* dstv = (float4*)tile;
  for (int i = threadIdx.x; i < tile_v; i += THREADS) {
    if (base_f + (long long)i * 4 + 3 < total_f) {       // full-tile in practice
      dstv[i] = src[i];
    }
  }
  __syncthreads();

  // ---- Compute: one thread per row ----
  const long long r = row0 + threadIdx.x;
  if (r >= nrows) return;
  const float* row = tile + threadIdx.x * ROW_F;

  float cx = row[0];
  float cy = row[1];
  float hw = row[2] * 0.5f;
  float hh = row[3] * 0.5f;
  float conf = row[4];

  float best = row[5];
  int bidx = 0;
#pragma unroll
  for (int c = 1; c < NCLS; ++c) {
    float v = row[5 + c];
    bool gt = v > best;            // strict > keeps FIRST max (jnp.argmax)
    best = gt ? v : best;
    bidx = gt ? c : bidx;
  }

  float score = conf * best;
  bool keep = score > CONF_THRESH;

  float o0 = keep ? cx - hw : 0.0f;
  float o1 = keep ? cy - hh : 0.0f;
  float o2 = keep ? cx + hw : 0.0f;
  float o3 = keep ? cy + hh : 0.0f;
  float o4 = keep ? score : 0.0f;
  float o5 = keep ? (float)bidx : 0.0f;

  float* op = out + r * 6;
  op[0] = o0;
  op[1] = o1;
  op[2] = o2;
  op[3] = o3;
  op[4] = o4;
  op[5] = o5;
}

extern "C" void kernel_launch(void* const* d_in, const int* in_sizes, int n_in,
                              void* d_out, int out_size, void* d_ws, size_t ws_size,
                              hipStream_t stream) {
  const float* in = (const float*)d_in[0];
  float* out = (float*)d_out;
  const int nrows = in_sizes[0] / ROW_F;                 // 16*25200 = 403200
  const int grid = (nrows + ROWS_PER_BLOCK - 1) / ROWS_PER_BLOCK;  // 3150
  yolo_post_kernel<<<grid, THREADS, 0, stream>>>(in, out, nrows);
}

// Round 2
// 192.385 us; speedup vs baseline: 1.1709x; 1.1709x over previous
//
#include <hip/hip_runtime.h>

#define ROWS_PER_BLOCK 128
#define THREADS 128
#define ROW_F 85        // floats per row
#define NCLS 80         // classes
#define CONF_THRESH 0.25f

#define TILE_F (ROWS_PER_BLOCK * ROW_F)   // 10880 floats
#define TILE_V (TILE_F / 4)               // 2720 float4
#define PER_THREAD 21                     // 128*21 = 2688; 32 extra vec4

// Block = 128 threads (2 waves). Stages 128 contiguous rows (43,520 B, 16 B
// aligned) into LDS. Staging is fully unrolled load-all-then-store-all so 21+
// float4 global loads per thread are simultaneously in flight (latency-bound
// -> BW-bound). LDS row stride 85 floats: t*85 % 32 = t*21 % 32 is a bank
// permutation (21 odd) -> compute-phase reads are conflict-free.
__global__ __launch_bounds__(THREADS) void yolo_post_kernel(
    const float* __restrict__ in, float* __restrict__ out, int nrows) {
  __shared__ float tile[TILE_F];

  const long long row0 = (long long)blockIdx.x * ROWS_PER_BLOCK;
  const long long base_f = row0 * ROW_F;
  const long long total_f = (long long)nrows * ROW_F;

  const float4* __restrict__ src = (const float4*)(in + base_f);
  float4* dstv = (float4*)tile;
  const int t = threadIdx.x;

  if (base_f + TILE_F <= total_f) {
    // ---- Fast path (always taken for nrows % 128 == 0): issue ALL loads,
    // then drain once, then all LDS writes. ----
    float4 v[PER_THREAD];
#pragma unroll
    for (int k = 0; k < PER_THREAD; ++k) {
      v[k] = src[t + k * THREADS];
    }
    float4 extra;
    if (t < TILE_V - PER_THREAD * THREADS) {   // 32 tail vec4
      extra = src[PER_THREAD * THREADS + t];
    }
#pragma unroll
    for (int k = 0; k < PER_THREAD; ++k) {
      dstv[t + k * THREADS] = v[k];
    }
    if (t < TILE_V - PER_THREAD * THREADS) {
      dstv[PER_THREAD * THREADS + t] = extra;
    }
  } else {
    // ---- Guarded tail path ----
    for (int i = t; i < TILE_V; i += THREADS) {
      if (base_f + (long long)i * 4 + 3 < total_f) dstv[i] = src[i];
    }
  }
  __syncthreads();

  // ---- Compute: one thread per row ----
  const long long r = row0 + t;
  if (r >= nrows) return;
  const float* row = tile + t * ROW_F;

  float cx = row[0];
  float cy = row[1];
  float hw = row[2] * 0.5f;
  float hh = row[3] * 0.5f;
  float conf = row[4];

  float best = row[5];
  int bidx = 0;
#pragma unroll
  for (int c = 1; c < NCLS; ++c) {
    float v = row[5 + c];
    bool gt = v > best;            // strict > keeps FIRST max (jnp.argmax)
    best = gt ? v : best;
    bidx = gt ? c : bidx;
  }

  float score = conf * best;
  bool keep = score > CONF_THRESH;

  float o0 = keep ? cx - hw : 0.0f;
  float o1 = keep ? cy - hh : 0.0f;
  float o2 = keep ? cx + hw : 0.0f;
  float o3 = keep ? cy + hh : 0.0f;
  float o4 = keep ? score : 0.0f;
  float o5 = keep ? (float)bidx : 0.0f;

  float* op = out + r * 6;
  op[0] = o0;
  op[1] = o1;
  op[2] = o2;
  op[3] = o3;
  op[4] = o4;
  op[5] = o5;
}

extern "C" void kernel_launch(void* const* d_in, const int* in_sizes, int n_in,
                              void* d_out, int out_size, void* d_ws, size_t ws_size,
                              hipStream_t stream) {
  const float* in = (const float*)d_in[0];
  float* out = (float*)d_out;
  const int nrows = in_sizes[0] / ROW_F;                 // 403200
  const int grid = (nrows + ROWS_PER_BLOCK - 1) / ROWS_PER_BLOCK;  // 3150
  yolo_post_kernel<<<grid, THREADS, 0, stream>>>(in, out, nrows);
}

// Round 3
// 192.083 us; speedup vs baseline: 1.1727x; 1.0016x over previous
//
#include <hip/hip_runtime.h>

#define ROWS_PER_BLOCK 64
#define THREADS 64
#define ROW_F 85        // floats per row
#define NCLS 80         // classes
#define CONF_THRESH 0.25f

#define TILE_F (ROWS_PER_BLOCK * ROW_F)   // 5440 floats = 21,760 B
#define TILE_V (TILE_F / 4)               // 1360 float4
#define PER_THREAD 21                     // 64*21 = 1344; 16 tail vec4
#define TAIL_V (TILE_V - PER_THREAD * THREADS)  // 16

// One wave (64 threads) per block, 64 rows per block, 21,760 B LDS ->
// 7 independent blocks/CU (vs 3 before). Single-wave blocks mean the
// stage->compute barrier has no cross-wave coupling, so the 7 resident
// blocks' load/compute/store phases overlap freely. Staging is fully
// unrolled load-all-then-store-all: 21 float4 loads per lane in flight
// (21 KB/wave, 147 KB/CU >> latency-BW product). LDS row stride 85:
// t*85 % 32 = t*21 % 32 is a bank permutation (21 odd) -> conflict-free.
__global__ __launch_bounds__(THREADS) void yolo_post_kernel(
    const float* __restrict__ in, float* __restrict__ out, int nrows) {
  __shared__ float tile[TILE_F];

  const long long row0 = (long long)blockIdx.x * ROWS_PER_BLOCK;
  const long long base_f = row0 * ROW_F;
  const long long total_f = (long long)nrows * ROW_F;

  const float4* __restrict__ src = (const float4*)(in + base_f);
  float4* dstv = (float4*)tile;
  const int t = threadIdx.x;

  if (base_f + TILE_F <= total_f) {
    // Fast path (always taken when nrows % 64 == 0): issue ALL loads,
    // drain once, then all LDS writes.
    float4 v[PER_THREAD];
#pragma unroll
    for (int k = 0; k < PER_THREAD; ++k) {
      v[k] = src[t + k * THREADS];
    }
    float4 extra;
    if (t < TAIL_V) {
      extra = src[PER_THREAD * THREADS + t];
    }
#pragma unroll
    for (int k = 0; k < PER_THREAD; ++k) {
      dstv[t + k * THREADS] = v[k];
    }
    if (t < TAIL_V) {
      dstv[PER_THREAD * THREADS + t] = extra;
    }
  } else {
    // Guarded tail path (general nrows)
    for (int i = t; i < TILE_V; i += THREADS) {
      if (base_f + (long long)i * 4 + 3 < total_f) dstv[i] = src[i];
    }
  }
  __syncthreads();   // single-wave block: compiles to a waitcnt, no coupling

  // ---- Compute: one thread per row ----
  const long long r = row0 + t;
  if (r >= nrows) return;
  const float* row = tile + t * ROW_F;

  float cx = row[0];
  float cy = row[1];
  float hw = row[2] * 0.5f;
  float hh = row[3] * 0.5f;
  float conf = row[4];

  float best = row[5];
  int bidx = 0;
#pragma unroll
  for (int c = 1; c < NCLS; ++c) {
    float v = row[5 + c];
    bool gt = v > best;            // strict > keeps FIRST max (jnp.argmax)
    best = gt ? v : best;
    bidx = gt ? c : bidx;
  }

  float score = conf * best;
  bool keep = score > CONF_THRESH;

  float o0 = keep ? cx - hw : 0.0f;
  float o1 = keep ? cy - hh : 0.0f;
  float o2 = keep ? cx + hw : 0.0f;
  float o3 = keep ? cy + hh : 0.0f;
  float o4 = keep ? score : 0.0f;
  float o5 = keep ? (float)bidx : 0.0f;

  float* op = out + r * 6;
  op[0] = o0;
  op[1] = o1;
  op[2] = o2;
  op[3] = o3;
  op[4] = o4;
  op[5] = o5;
}

extern "C" void kernel_launch(void* const* d_in, const int* in_sizes, int n_in,
                              void* d_out, int out_size, void* d_ws, size_t ws_size,
                              hipStream_t stream) {
  const float* in = (const float*)d_in[0];
  float* out = (float*)d_out;
  const int nrows = in_sizes[0] / ROW_F;                 // 403200
  const int grid = (nrows + ROWS_PER_BLOCK - 1) / ROWS_PER_BLOCK;  // 6300
  yolo_post_kernel<<<grid, THREADS, 0, stream>>>(in, out, nrows);
}